// Round 4
// baseline (712.662 us; speedup 1.0000x reference)
//
#include <hip/hip_runtime.h>
#include <stdint.h>

#define NN 10000
#define NE 50000
#define KTOT 4224   // 4096 (S) + 64 (hs/bias) + 64 (h/root)
#define SPLITK 22
#define KCH 192     // KTOT / SPLITK = 12 k-tiles of 16
#define KTILES 12

// h = relu(x @ lin0_w + lin0_b)   [10000,20]@[20,64]
__global__ void k_lin0(const float* __restrict__ x, const float* __restrict__ w,
                       const float* __restrict__ b, float* __restrict__ h) {
  int idx = blockIdx.x * blockDim.x + threadIdx.x;
  if (idx >= NN * 64) return;
  int n = idx >> 6, o = idx & 63;
  float acc = b[o];
  const float* xr = x + n * 20;
#pragma unroll
  for (int j = 0; j < 20; ++j) acc += xr[j] * w[j * 64 + o];
  h[idx] = acc > 0.f ? acc : 0.f;
}

// u = relu(edge_attr @ nn1_w + nn1_b)   [50000,5]@[5,64]
__global__ void k_eh(const float* __restrict__ ea, const float* __restrict__ w,
                     const float* __restrict__ b, float* __restrict__ u) {
  int idx = blockIdx.x * blockDim.x + threadIdx.x;
  if (idx >= NE * 64) return;
  int e = idx >> 6, o = idx & 63;
  float acc = b[o];
  const float* er = ea + e * 5;
#pragma unroll
  for (int j = 0; j < 5; ++j) acc += er[j] * w[j * 64 + o];
  u[idx] = acc > 0.f ? acc : 0.f;
}

// edge_index arrives as int32: src = ei[0..NE), dst = ei[NE..2NE)
__global__ void k_deg(const int* __restrict__ ei, int* __restrict__ deg) {
  int e = blockIdx.x * blockDim.x + threadIdx.x;
  if (e < NE) atomicAdd(&deg[ei[NE + e]], 1);
}

// exclusive scan of deg -> offs[0..NN], plus inv_denom = 1/max(deg,1)
__global__ void k_scan(const int* __restrict__ deg, int* __restrict__ offs,
                       float* __restrict__ inv_denom) {
  __shared__ int s[256];
  int t = threadIdx.x;
  int base = t * 40;
  int sum = 0;
  for (int j = 0; j < 40; ++j) {
    int n = base + j;
    sum += (n < NN) ? deg[n] : 0;
  }
  s[t] = sum;
  __syncthreads();
  for (int off = 1; off < 256; off <<= 1) {
    int v = (t >= off) ? s[t - off] : 0;
    __syncthreads();
    s[t] += v;
    __syncthreads();
  }
  int run = s[t] - sum;  // exclusive prefix for this thread's chunk
  for (int j = 0; j < 40; ++j) {
    int n = base + j;
    if (n < NN) {
      offs[n] = run;
      int d = deg[n];
      run += d;
      inv_denom[n] = 1.0f / (float)(d > 0 ? d : 1);
    }
  }
  if (t == 255) offs[NN] = s[255];
}

__global__ void k_csr(const int* __restrict__ ei, const int* __restrict__ offs,
                      int* __restrict__ cursor, int* __restrict__ csr_src,
                      int* __restrict__ csr_eid) {
  int e = blockIdx.x * blockDim.x + threadIdx.x;
  if (e >= NE) return;
  int d = ei[NE + e];
  int pos = offs[d] + atomicAdd(&cursor[d], 1);
  csr_src[pos] = ei[e];
  csr_eid[pos] = e;
}

// WF [4224,64]: rows 0..4095: nn2_w permuted; 4096..4159: nn2_b; 4160..4223: root_w
__global__ void k_wf(const float* __restrict__ w2, const float* __restrict__ b2,
                     const float* __restrict__ rootw, float* __restrict__ wf) {
  int idx = blockIdx.x * blockDim.x + threadIdx.x;
  if (idx >= KTOT * 64) return;
  int r = idx >> 6, o = idx & 63;
  float v;
  if (r < 4096) {
    int k = r >> 6, i = r & 63;
    v = w2[k * 4096 + i * 64 + o];
  } else if (r < 4160) {
    int i = r - 4096;
    v = b2[i * 64 + o];
  } else {
    int i = r - 4160;
    v = rootw[i * 64 + o];
  }
  wf[idx] = v;
}

// Per node: SV row = [ inv_d * S(k,i) (4096) | inv_d * hs(i) (64) | h[n] (64) ]
__global__ void __launch_bounds__(256) k_scatter(
    const float* __restrict__ h, const float* __restrict__ u,
    const int* __restrict__ offs, const int* __restrict__ csr_src,
    const int* __restrict__ csr_eid, const float* __restrict__ inv_denom,
    float* __restrict__ sv, int chunk_start) {
  int n = chunk_start + blockIdx.x;
  int t = threadIdx.x;
  int beg = offs[n], end = offs[n + 1];
  float invd = inv_denom[n];
  __shared__ float u_s[16][64];
  __shared__ float h_s[16][64];
  __shared__ int eid_s[16], src_s[16];
  float acc[16];
#pragma unroll
  for (int j = 0; j < 16; ++j) acc[j] = 0.f;
  float hsacc = 0.f;
  const int k = t >> 2;           // (t*16)>>6
  const int i0 = (t & 3) << 4;    // (t*16)&63
  for (int c = beg; c < end; c += 16) {
    int cnt = end - c; if (cnt > 16) cnt = 16;
    if (t < 16) {
      eid_s[t] = (t < cnt) ? csr_eid[c + t] : 0;
      src_s[t] = (t < cnt) ? csr_src[c + t] : 0;
    }
    __syncthreads();
#pragma unroll
    for (int j = 0; j < 4; ++j) {
      int f = j * 256 + t;
      int e = f >> 6, col = f & 63;
      u_s[e][col] = (e < cnt) ? u[(size_t)eid_s[e] * 64 + col] : 0.f;
      h_s[e][col] = (e < cnt) ? h[(size_t)src_s[e] * 64 + col] : 0.f;
    }
    __syncthreads();
    for (int e = 0; e < cnt; ++e) {
      float uv = u_s[e][k];
#pragma unroll
      for (int j = 0; j < 16; ++j) acc[j] += uv * h_s[e][i0 + j];
    }
    if (t < 64) {
      for (int e = 0; e < cnt; ++e) hsacc += h_s[e][t];
    }
    __syncthreads();
  }
  size_t row = (size_t)(n - chunk_start) * KTOT;
  float4* sv4 = (float4*)(sv + row);
#pragma unroll
  for (int j4 = 0; j4 < 4; ++j4) {
    sv4[t * 4 + j4] = make_float4(acc[j4 * 4 + 0] * invd, acc[j4 * 4 + 1] * invd,
                                  acc[j4 * 4 + 2] * invd, acc[j4 * 4 + 3] * invd);
  }
  if (t < 64) {
    sv[row + 4096 + t] = hsacc * invd;
    sv[row + 4160 + t] = h[(size_t)n * 64 + t];
  }
}

// Split-K GEMM: part[kc][node][o] += SV[node, kc*KCH .. ) @ WF
// BM=256, BN=64, BK=16, 256 threads, 8m x 8o per thread (2.0 FLOP / LDS-byte)
__global__ void __launch_bounds__(256) k_gemm3(
    const float* __restrict__ sv, const float* __restrict__ wf,
    float* __restrict__ part, int chunk_start, int chunk_nodes) {
  __shared__ float A_s[16][260];  // [kk][m]; stride 260: 16B-aligned rows, 2-way max on write
  __shared__ float W_s[16][64];   // [kk][o]
  int t = threadIdx.x;
  int node0 = blockIdx.x * 256;
  int kc = blockIdx.y;
  const int og8 = (t & 7) * 8;
  const int mg8 = (t >> 3) * 8;
  float acc[8][8] = {};
  for (int kt = 0; kt < KTILES; ++kt) {
    int kb = kc * KCH + kt * 16;
    // stage A: 256 nodes x 16 k; thread loads one float4 per j
#pragma unroll
    for (int j = 0; j < 4; ++j) {
      int m = j * 64 + (t >> 2);
      int c4 = (t & 3) * 4;
      int node = node0 + m;
      float4 v = make_float4(0.f, 0.f, 0.f, 0.f);
      if (node < chunk_nodes) v = *(const float4*)&sv[(size_t)node * KTOT + kb + c4];
      A_s[c4 + 0][m] = v.x; A_s[c4 + 1][m] = v.y;
      A_s[c4 + 2][m] = v.z; A_s[c4 + 3][m] = v.w;
    }
    // stage W: 16 x 64
    {
      int r = t >> 4, c = (t & 15) * 4;
      *(float4*)&W_s[r][c] = *(const float4*)&wf[(size_t)(kb + r) * 64 + c];
    }
    __syncthreads();
#pragma unroll
    for (int kk = 0; kk < 16; ++kk) {
      const float4 a0 = *(const float4*)&A_s[kk][mg8];
      const float4 a1 = *(const float4*)&A_s[kk][mg8 + 4];
      const float4 w0 = *(const float4*)&W_s[kk][og8];
      const float4 w1 = *(const float4*)&W_s[kk][og8 + 4];
      float am[8] = {a0.x, a0.y, a0.z, a0.w, a1.x, a1.y, a1.z, a1.w};
      float wo[8] = {w0.x, w0.y, w0.z, w0.w, w1.x, w1.y, w1.z, w1.w};
#pragma unroll
      for (int mm = 0; mm < 8; ++mm)
#pragma unroll
        for (int oo = 0; oo < 8; ++oo)
          acc[mm][oo] += am[mm] * wo[oo];
    }
    __syncthreads();
  }
  size_t pbase = (size_t)kc * NN * 64;
#pragma unroll
  for (int mm = 0; mm < 8; ++mm) {
    int node = node0 + (mg8 & ~7) + mm;  // node0 + mg8 + mm
    if (node < chunk_nodes) {
      float* dst = &part[pbase + (size_t)(chunk_start + node) * 64 + og8];
      *(float4*)dst = make_float4(acc[mm][0], acc[mm][1], acc[mm][2], acc[mm][3]);
      *(float4*)(dst + 4) = make_float4(acc[mm][4], acc[mm][5], acc[mm][6], acc[mm][7]);
    }
  }
}

// h_new = relu(sum_k part + conv_b)
__global__ void k_epi(const float* __restrict__ part, const float* __restrict__ cb,
                      float* __restrict__ hout) {
  int idx = blockIdx.x * blockDim.x + threadIdx.x;
  if (idx >= NN * 64) return;
  int o = idx & 63;
  float acc = cb[o];
#pragma unroll
  for (int kc = 0; kc < SPLITK; ++kc) acc += part[(size_t)kc * NN * 64 + idx];
  hout[idx] = acc > 0.f ? acc : 0.f;
}

// partial node-sum: part[160][64]
__global__ void k_sum_p(const float* __restrict__ h, float* __restrict__ part) {
  __shared__ float s[256];
  int t = threadIdx.x, b = blockIdx.x;
  int o = t & 63, g = t >> 6;
  float acc = 0.f;
  for (int k = 0;; ++k) {
    int n = b + 160 * (g + 4 * k);
    if (n >= NN) break;
    acc += h[(size_t)n * 64 + o];
  }
  s[t] = acc;
  __syncthreads();
  if (t < 64) part[(size_t)b * 64 + t] = s[t] + s[64 + t] + s[128 + t] + s[192 + t];
}

// reduce partials -> concat -> bneck (69 -> 384), one block of 384
__global__ void __launch_bounds__(384) k_bneck(
    const float* __restrict__ part, const float* __restrict__ vpa,
    const float* __restrict__ mz, const float* __restrict__ adduct,
    const float* __restrict__ bw, const float* __restrict__ bb,
    float* __restrict__ aout) {
  __shared__ float in69[69];
  __shared__ float red[256];
  int t = threadIdx.x;
  if (t < 256) {
    int o = t & 63, g = t >> 6;
    float acc = 0.f;
    for (int k = 0; k < 40; ++k) acc += part[(size_t)(g * 40 + k) * 64 + o];
    red[t] = acc;
  }
  __syncthreads();
  if (t < 64) in69[t] = red[t] + red[64 + t] + red[128 + t] + red[192 + t];
  if (t == 64) in69[64] = vpa[0];
  if (t == 65) in69[65] = mz[0];
  if (t >= 66 && t < 69) in69[t] = adduct[t - 66];
  __syncthreads();
  float acc = bb[t];
#pragma unroll 4
  for (int i = 0; i < 69; ++i) acc += in69[i] * bw[i * 384 + t];
  aout[t] = acc > 0.f ? acc : 0.f;
}

// one 384->384 relu layer, 24 blocks x 256 threads, 16 outputs/block
__global__ void __launch_bounds__(256) k_layer(
    const float* __restrict__ ain, const float* __restrict__ w,
    const float* __restrict__ bias, float* __restrict__ aout) {
  __shared__ float a_s[384];
  __shared__ float red[256];
  int t = threadIdx.x;
  for (int i = t; i < 384; i += 256) a_s[i] = ain[i];
  __syncthreads();
  int o = blockIdx.x * 16 + (t & 15);
  int ig = t >> 4;  // 0..15
  float acc = 0.f;
#pragma unroll
  for (int k = 0; k < 24; ++k) {
    int i = ig + (k << 4);
    acc += a_s[i] * w[i * 384 + o];
  }
  red[t] = acc;
  __syncthreads();
  if (t < 128) red[t] += red[t + 128];
  __syncthreads();
  if (t < 64) red[t] += red[t + 64];
  __syncthreads();
  if (t < 32) red[t] += red[t + 32];
  __syncthreads();
  if (t < 16) {
    float v = red[t] + red[t + 16] + bias[o];
    aout[o] = v > 0.f ? v : 0.f;
  }
}

// final: act @ l2w + l2b -> scalar
__global__ void __launch_bounds__(384) k_out(
    const float* __restrict__ act, const float* __restrict__ l2w,
    const float* __restrict__ l2b, float* __restrict__ out) {
  __shared__ float red[384];
  int t = threadIdx.x;
  red[t] = act[t] * l2w[t];
  __syncthreads();
  if (t < 128) red[t] += red[t + 128] + red[t + 256];
  __syncthreads();
  if (t < 64) {
    float s2 = red[t] + red[t + 64];
#pragma unroll
    for (int off = 32; off; off >>= 1) s2 += __shfl_down(s2, off);
    if (t == 0) out[0] = s2 + l2b[0];
  }
}

extern "C" void kernel_launch(void* const* d_in, const int* in_sizes, int n_in,
                              void* d_out, int out_size, void* d_ws, size_t ws_size,
                              hipStream_t stream) {
  const float* x      = (const float*)d_in[0];
  const int* ei       = (const int*)d_in[1];   // int32 on device
  const float* ea     = (const float*)d_in[2];
  const float* vpa    = (const float*)d_in[3];
  const float* mz     = (const float*)d_in[4];
  const float* adduct = (const float*)d_in[5];
  const float* lin0_w = (const float*)d_in[6];
  const float* lin0_b = (const float*)d_in[7];
  const float* nn1_w  = (const float*)d_in[8];
  const float* nn1_b  = (const float*)d_in[9];
  const float* nn2_w  = (const float*)d_in[10];
  const float* nn2_b  = (const float*)d_in[11];
  const float* root_w = (const float*)d_in[12];
  const float* conv_b = (const float*)d_in[13];
  const float* bw     = (const float*)d_in[14];
  const float* bb     = (const float*)d_in[15];
  const float* l1w    = (const float*)d_in[16];
  const float* l1b    = (const float*)d_in[17];
  const float* l2w    = (const float*)d_in[18];
  const float* l2b    = (const float*)d_in[19];

  char* p = (char*)d_ws;
  auto alloc = [&](size_t bytes) {
    char* r = p;
    p += (bytes + 255) & ~(size_t)255;
    return r;
  };
  float* h0      = (float*)alloc((size_t)NN * 64 * 4);
  float* h1      = (float*)alloc((size_t)NN * 64 * 4);
  float* u       = (float*)alloc((size_t)NE * 64 * 4);
  float* wf      = (float*)alloc((size_t)KTOT * 64 * 4);
  int* deg       = (int*)alloc(NN * 4);
  int* offs      = (int*)alloc((NN + 1) * 4);
  int* cursor    = (int*)alloc(NN * 4);
  float* invd    = (float*)alloc(NN * 4);
  int* csr_src   = (int*)alloc(NE * 4);
  int* csr_eid   = (int*)alloc(NE * 4);
  float* part    = (float*)alloc(160 * 64 * 4);
  float* kpart   = (float*)alloc((size_t)SPLITK * NN * 64 * 4);
  float* actA    = (float*)alloc(384 * 4);
  float* actB    = (float*)alloc(384 * 4);
  size_t used = (size_t)(p - (char*)d_ws);
  size_t avail = ws_size > used ? ws_size - used : 0;
  long long CH = (long long)(avail / ((size_t)KTOT * 4));
  if (CH > NN) CH = NN;
  if (CH < 1) CH = 1;
  float* sv = (float*)p;

  hipMemsetAsync(deg, 0, NN * 4, stream);
  hipMemsetAsync(cursor, 0, NN * 4, stream);

  k_lin0<<<(NN * 64 + 255) / 256, 256, 0, stream>>>(x, lin0_w, lin0_b, h0);
  k_eh<<<(NE * 64 + 255) / 256, 256, 0, stream>>>(ea, nn1_w, nn1_b, u);
  k_deg<<<(NE + 255) / 256, 256, 0, stream>>>(ei, deg);
  k_scan<<<1, 256, 0, stream>>>(deg, offs, invd);
  k_csr<<<(NE + 255) / 256, 256, 0, stream>>>(ei, offs, cursor, csr_src, csr_eid);
  k_wf<<<(KTOT * 64 + 255) / 256, 256, 0, stream>>>(nn2_w, nn2_b, root_w, wf);

  float* hc = h0;
  float* hn = h1;
  for (int it = 0; it < 3; ++it) {
    for (int cs = 0; cs < NN; cs += (int)CH) {
      int cn = (NN - cs < (int)CH) ? (NN - cs) : (int)CH;
      k_scatter<<<cn, 256, 0, stream>>>(hc, u, offs, csr_src, csr_eid, invd, sv, cs);
      dim3 g3((cn + 255) / 256, SPLITK);
      k_gemm3<<<g3, 256, 0, stream>>>(sv, wf, kpart, cs, cn);
    }
    k_epi<<<(NN * 64 + 255) / 256, 256, 0, stream>>>(kpart, conv_b, hn);
    float* tmp = hc; hc = hn; hn = tmp;
  }
  k_sum_p<<<160, 256, 0, stream>>>(hc, part);
  k_bneck<<<1, 384, 0, stream>>>(part, vpa, mz, adduct, bw, bb, actA);
  float* ain = actA;
  float* aout = actB;
  for (int L = 0; L < 6; ++L) {
    k_layer<<<24, 256, 0, stream>>>(ain, l1w, l1b, aout);
    float* tmp = ain; ain = aout; aout = tmp;
  }
  k_out<<<1, 384, 0, stream>>>(ain, l2w, l2b, (float*)d_out);
}

// Round 5
// 534.932 us; speedup vs baseline: 1.3322x; 1.3322x over previous
//
#include <hip/hip_runtime.h>
#include <stdint.h>

#define NN 10000
#define NE 50000
#define KTOT 4224   // 4096 (S) + 64 (hs/bias) + 64 (h/root)
#define SPLITK 11
#define KCH 384     // KTOT / SPLITK = 6 k-tiles of 64

// h = relu(x @ lin0_w + lin0_b)   [10000,20]@[20,64]
__global__ void k_lin0(const float* __restrict__ x, const float* __restrict__ w,
                       const float* __restrict__ b, float* __restrict__ h) {
  int idx = blockIdx.x * blockDim.x + threadIdx.x;
  if (idx >= NN * 64) return;
  int n = idx >> 6, o = idx & 63;
  float acc = b[o];
  const float* xr = x + n * 20;
#pragma unroll
  for (int j = 0; j < 20; ++j) acc += xr[j] * w[j * 64 + o];
  h[idx] = acc > 0.f ? acc : 0.f;
}

// u = relu(edge_attr @ nn1_w + nn1_b)   [50000,5]@[5,64]
__global__ void k_eh(const float* __restrict__ ea, const float* __restrict__ w,
                     const float* __restrict__ b, float* __restrict__ u) {
  int idx = blockIdx.x * blockDim.x + threadIdx.x;
  if (idx >= NE * 64) return;
  int e = idx >> 6, o = idx & 63;
  float acc = b[o];
  const float* er = ea + e * 5;
#pragma unroll
  for (int j = 0; j < 5; ++j) acc += er[j] * w[j * 64 + o];
  u[idx] = acc > 0.f ? acc : 0.f;
}

// edge_index arrives as int32: src = ei[0..NE), dst = ei[NE..2NE)
__global__ void k_deg(const int* __restrict__ ei, int* __restrict__ deg) {
  int e = blockIdx.x * blockDim.x + threadIdx.x;
  if (e < NE) atomicAdd(&deg[ei[NE + e]], 1);
}

// exclusive scan of deg -> offs[0..NN], plus inv_denom = 1/max(deg,1)
__global__ void k_scan(const int* __restrict__ deg, int* __restrict__ offs,
                       float* __restrict__ inv_denom) {
  __shared__ int s[256];
  int t = threadIdx.x;
  int base = t * 40;
  int sum = 0;
  for (int j = 0; j < 40; ++j) {
    int n = base + j;
    sum += (n < NN) ? deg[n] : 0;
  }
  s[t] = sum;
  __syncthreads();
  for (int off = 1; off < 256; off <<= 1) {
    int v = (t >= off) ? s[t - off] : 0;
    __syncthreads();
    s[t] += v;
    __syncthreads();
  }
  int run = s[t] - sum;  // exclusive prefix for this thread's chunk
  for (int j = 0; j < 40; ++j) {
    int n = base + j;
    if (n < NN) {
      offs[n] = run;
      int d = deg[n];
      run += d;
      inv_denom[n] = 1.0f / (float)(d > 0 ? d : 1);
    }
  }
  if (t == 255) offs[NN] = s[255];
}

__global__ void k_csr(const int* __restrict__ ei, const int* __restrict__ offs,
                      int* __restrict__ cursor, int* __restrict__ csr_src,
                      int* __restrict__ csr_eid) {
  int e = blockIdx.x * blockDim.x + threadIdx.x;
  if (e >= NE) return;
  int d = ei[NE + e];
  int pos = offs[d] + atomicAdd(&cursor[d], 1);
  csr_src[pos] = ei[e];
  csr_eid[pos] = e;
}

// WF [4224,64]: rows 0..4095: nn2_w permuted; 4096..4159: nn2_b; 4160..4223: root_w
__global__ void k_wf(const float* __restrict__ w2, const float* __restrict__ b2,
                     const float* __restrict__ rootw, float* __restrict__ wf) {
  int idx = blockIdx.x * blockDim.x + threadIdx.x;
  if (idx >= KTOT * 64) return;
  int r = idx >> 6, o = idx & 63;
  float v;
  if (r < 4096) {
    int k = r >> 6, i = r & 63;
    v = w2[k * 4096 + i * 64 + o];
  } else if (r < 4160) {
    int i = r - 4096;
    v = b2[i * 64 + o];
  } else {
    int i = r - 4160;
    v = rootw[i * 64 + o];
  }
  wf[idx] = v;
}

// Per node: SV row = [ inv_d * S(k,i) (4096) | inv_d * hs(i) (64) | h[n] (64) ]
__global__ void __launch_bounds__(256) k_scatter(
    const float* __restrict__ h, const float* __restrict__ u,
    const int* __restrict__ offs, const int* __restrict__ csr_src,
    const int* __restrict__ csr_eid, const float* __restrict__ inv_denom,
    float* __restrict__ sv, int chunk_start) {
  int n = chunk_start + blockIdx.x;
  int t = threadIdx.x;
  int beg = offs[n], end = offs[n + 1];
  float invd = inv_denom[n];
  __shared__ float u_s[16][64];
  __shared__ float h_s[16][64];
  __shared__ int eid_s[16], src_s[16];
  float acc[16];
#pragma unroll
  for (int j = 0; j < 16; ++j) acc[j] = 0.f;
  float hsacc = 0.f;
  const int k = t >> 2;           // (t*16)>>6
  const int i0 = (t & 3) << 4;    // (t*16)&63
  for (int c = beg; c < end; c += 16) {
    int cnt = end - c; if (cnt > 16) cnt = 16;
    if (t < 16) {
      eid_s[t] = (t < cnt) ? csr_eid[c + t] : 0;
      src_s[t] = (t < cnt) ? csr_src[c + t] : 0;
    }
    __syncthreads();
#pragma unroll
    for (int j = 0; j < 4; ++j) {
      int f = j * 256 + t;
      int e = f >> 6, col = f & 63;
      u_s[e][col] = (e < cnt) ? u[(size_t)eid_s[e] * 64 + col] : 0.f;
      h_s[e][col] = (e < cnt) ? h[(size_t)src_s[e] * 64 + col] : 0.f;
    }
    __syncthreads();
    for (int e = 0; e < cnt; ++e) {
      float uv = u_s[e][k];
#pragma unroll
      for (int j = 0; j < 16; ++j) acc[j] += uv * h_s[e][i0 + j];
    }
    if (t < 64) {
      for (int e = 0; e < cnt; ++e) hsacc += h_s[e][t];
    }
    __syncthreads();
  }
  size_t row = (size_t)(n - chunk_start) * KTOT;
  float4* sv4 = (float4*)(sv + row);
#pragma unroll
  for (int j4 = 0; j4 < 4; ++j4) {
    sv4[t * 4 + j4] = make_float4(acc[j4 * 4 + 0] * invd, acc[j4 * 4 + 1] * invd,
                                  acc[j4 * 4 + 2] * invd, acc[j4 * 4 + 3] * invd);
  }
  if (t < 64) {
    sv[row + 4096 + t] = hsacc * invd;
    sv[row + 4160 + t] = h[(size_t)n * 64 + t];
  }
}

// Split-K GEMM: part[kc][node][o] = SV[node, kc*384 .. +384) @ WF[same rows, :]
// BM=64, BN=64, BK=64, 256 threads, 4m x 4o per thread.
// A stored [m][k] (NO transpose on staging), inner loop k-vectorized:
// all LDS traffic is aligned float4; staging writes bank-balanced; A reads
// broadcast (4 unique addrs/wave); W reads 16-unique (dedup).
__global__ void __launch_bounds__(256) k_gemm2(
    const float* __restrict__ sv, const float* __restrict__ wf,
    float* __restrict__ part, int chunk_start, int chunk_nodes) {
  __shared__ float A_s[64][68];  // [m][k], row stride 272 B (16B-aligned)
  __shared__ float W_s[64][68];  // [k][o], row stride 272 B
  int t = threadIdx.x;
  int node0 = blockIdx.x * 64;
  int kc = blockIdx.y;           // 0..SPLITK-1
  int m4 = (t >> 4) * 4;         // 0..60
  int o4 = (t & 15) * 4;         // 0..60
  float acc[4][4] = {};
  for (int kt = 0; kt < KCH / 64; ++kt) {
    int kb = kc * KCH + kt * 64;
    // stage A: 64 nodes x 64 k, direct float4 (no transpose)
#pragma unroll
    for (int j = 0; j < 4; ++j) {
      int idx = j * 1024 + t * 4;
      int m = idx >> 6, c4 = idx & 63;
      int node = node0 + m;
      float4 v = make_float4(0.f, 0.f, 0.f, 0.f);
      if (node < chunk_nodes) v = *(const float4*)&sv[(size_t)node * KTOT + kb + c4];
      *(float4*)&A_s[m][c4] = v;
    }
    // stage W: 64 k x 64 o, direct float4
#pragma unroll
    for (int j = 0; j < 4; ++j) {
      int idx = j * 1024 + t * 4;
      int r = idx >> 6, c4 = idx & 63;
      *(float4*)&W_s[r][c4] = *(const float4*)&wf[(size_t)(kb + r) * 64 + c4];
    }
    __syncthreads();
#pragma unroll 2
    for (int kk = 0; kk < 64; kk += 4) {
      float4 w0 = *(const float4*)&W_s[kk + 0][o4];
      float4 w1 = *(const float4*)&W_s[kk + 1][o4];
      float4 w2 = *(const float4*)&W_s[kk + 2][o4];
      float4 w3 = *(const float4*)&W_s[kk + 3][o4];
#pragma unroll
      for (int mm = 0; mm < 4; ++mm) {
        float4 a = *(const float4*)&A_s[m4 + mm][kk];
        acc[mm][0] += a.x * w0.x + a.y * w1.x + a.z * w2.x + a.w * w3.x;
        acc[mm][1] += a.x * w0.y + a.y * w1.y + a.z * w2.y + a.w * w3.y;
        acc[mm][2] += a.x * w0.z + a.y * w1.z + a.z * w2.z + a.w * w3.z;
        acc[mm][3] += a.x * w0.w + a.y * w1.w + a.z * w2.w + a.w * w3.w;
      }
    }
    __syncthreads();
  }
#pragma unroll
  for (int mm = 0; mm < 4; ++mm) {
    int node = node0 + m4 + mm;
    if (node < chunk_nodes) {
      float4 v = make_float4(acc[mm][0], acc[mm][1], acc[mm][2], acc[mm][3]);
      *(float4*)&part[(size_t)kc * NN * 64 + (size_t)(chunk_start + node) * 64 + o4] = v;
    }
  }
}

// h_new = relu(sum_k part + conv_b)
__global__ void k_epi(const float* __restrict__ part, const float* __restrict__ cb,
                      float* __restrict__ hout) {
  int idx = blockIdx.x * blockDim.x + threadIdx.x;
  if (idx >= NN * 64) return;
  int o = idx & 63;
  float acc = cb[o];
#pragma unroll
  for (int kc = 0; kc < SPLITK; ++kc) acc += part[(size_t)kc * NN * 64 + idx];
  hout[idx] = acc > 0.f ? acc : 0.f;
}

// partial node-sum: part[160][64]
__global__ void k_sum_p(const float* __restrict__ h, float* __restrict__ part) {
  __shared__ float s[256];
  int t = threadIdx.x, b = blockIdx.x;
  int o = t & 63, g = t >> 6;
  float acc = 0.f;
  for (int k = 0;; ++k) {
    int n = b + 160 * (g + 4 * k);
    if (n >= NN) break;
    acc += h[(size_t)n * 64 + o];
  }
  s[t] = acc;
  __syncthreads();
  if (t < 64) part[(size_t)b * 64 + t] = s[t] + s[64 + t] + s[128 + t] + s[192 + t];
}

// reduce partials -> concat -> bneck (69 -> 384), one block of 384
__global__ void __launch_bounds__(384) k_bneck(
    const float* __restrict__ part, const float* __restrict__ vpa,
    const float* __restrict__ mz, const float* __restrict__ adduct,
    const float* __restrict__ bw, const float* __restrict__ bb,
    float* __restrict__ aout) {
  __shared__ float in69[69];
  __shared__ float red[256];
  int t = threadIdx.x;
  if (t < 256) {
    int o = t & 63, g = t >> 6;
    float acc = 0.f;
    for (int k = 0; k < 40; ++k) acc += part[(size_t)(g * 40 + k) * 64 + o];
    red[t] = acc;
  }
  __syncthreads();
  if (t < 64) in69[t] = red[t] + red[64 + t] + red[128 + t] + red[192 + t];
  if (t == 64) in69[64] = vpa[0];
  if (t == 65) in69[65] = mz[0];
  if (t >= 66 && t < 69) in69[t] = adduct[t - 66];
  __syncthreads();
  float acc = bb[t];
#pragma unroll 4
  for (int i = 0; i < 69; ++i) acc += in69[i] * bw[i * 384 + t];
  aout[t] = acc > 0.f ? acc : 0.f;
}

// one 384->384 relu layer, 24 blocks x 256 threads, 16 outputs/block
__global__ void __launch_bounds__(256) k_layer(
    const float* __restrict__ ain, const float* __restrict__ w,
    const float* __restrict__ bias, float* __restrict__ aout) {
  __shared__ float a_s[384];
  __shared__ float red[256];
  int t = threadIdx.x;
  for (int i = t; i < 384; i += 256) a_s[i] = ain[i];
  __syncthreads();
  int o = blockIdx.x * 16 + (t & 15);
  int ig = t >> 4;  // 0..15
  float acc = 0.f;
#pragma unroll
  for (int k = 0; k < 24; ++k) {
    int i = ig + (k << 4);
    acc += a_s[i] * w[i * 384 + o];
  }
  red[t] = acc;
  __syncthreads();
  if (t < 128) red[t] += red[t + 128];
  __syncthreads();
  if (t < 64) red[t] += red[t + 64];
  __syncthreads();
  if (t < 32) red[t] += red[t + 32];
  __syncthreads();
  if (t < 16) {
    float v = red[t] + red[t + 16] + bias[o];
    aout[o] = v > 0.f ? v : 0.f;
  }
}

// final: act @ l2w + l2b -> scalar
__global__ void __launch_bounds__(384) k_out(
    const float* __restrict__ act, const float* __restrict__ l2w,
    const float* __restrict__ l2b, float* __restrict__ out) {
  __shared__ float red[384];
  int t = threadIdx.x;
  red[t] = act[t] * l2w[t];
  __syncthreads();
  if (t < 128) red[t] += red[t + 128] + red[t + 256];
  __syncthreads();
  if (t < 64) {
    float s2 = red[t] + red[t + 64];
#pragma unroll
    for (int off = 32; off; off >>= 1) s2 += __shfl_down(s2, off);
    if (t == 0) out[0] = s2 + l2b[0];
  }
}

extern "C" void kernel_launch(void* const* d_in, const int* in_sizes, int n_in,
                              void* d_out, int out_size, void* d_ws, size_t ws_size,
                              hipStream_t stream) {
  const float* x      = (const float*)d_in[0];
  const int* ei       = (const int*)d_in[1];   // int32 on device
  const float* ea     = (const float*)d_in[2];
  const float* vpa    = (const float*)d_in[3];
  const float* mz     = (const float*)d_in[4];
  const float* adduct = (const float*)d_in[5];
  const float* lin0_w = (const float*)d_in[6];
  const float* lin0_b = (const float*)d_in[7];
  const float* nn1_w  = (const float*)d_in[8];
  const float* nn1_b  = (const float*)d_in[9];
  const float* nn2_w  = (const float*)d_in[10];
  const float* nn2_b  = (const float*)d_in[11];
  const float* root_w = (const float*)d_in[12];
  const float* conv_b = (const float*)d_in[13];
  const float* bw     = (const float*)d_in[14];
  const float* bb     = (const float*)d_in[15];
  const float* l1w    = (const float*)d_in[16];
  const float* l1b    = (const float*)d_in[17];
  const float* l2w    = (const float*)d_in[18];
  const float* l2b    = (const float*)d_in[19];

  char* p = (char*)d_ws;
  auto alloc = [&](size_t bytes) {
    char* r = p;
    p += (bytes + 255) & ~(size_t)255;
    return r;
  };
  float* h0      = (float*)alloc((size_t)NN * 64 * 4);
  float* h1      = (float*)alloc((size_t)NN * 64 * 4);
  float* u       = (float*)alloc((size_t)NE * 64 * 4);
  float* wf      = (float*)alloc((size_t)KTOT * 64 * 4);
  int* deg       = (int*)alloc(NN * 4);
  int* offs      = (int*)alloc((NN + 1) * 4);
  int* cursor    = (int*)alloc(NN * 4);
  float* invd    = (float*)alloc(NN * 4);
  int* csr_src   = (int*)alloc(NE * 4);
  int* csr_eid   = (int*)alloc(NE * 4);
  float* part    = (float*)alloc(160 * 64 * 4);
  float* kpart   = (float*)alloc((size_t)SPLITK * NN * 64 * 4);
  float* actA    = (float*)alloc(384 * 4);
  float* actB    = (float*)alloc(384 * 4);
  size_t used = (size_t)(p - (char*)d_ws);
  size_t avail = ws_size > used ? ws_size - used : 0;
  long long CH = (long long)(avail / ((size_t)KTOT * 4));
  if (CH > NN) CH = NN;
  if (CH < 1) CH = 1;
  float* sv = (float*)p;

  hipMemsetAsync(deg, 0, NN * 4, stream);
  hipMemsetAsync(cursor, 0, NN * 4, stream);

  k_lin0<<<(NN * 64 + 255) / 256, 256, 0, stream>>>(x, lin0_w, lin0_b, h0);
  k_eh<<<(NE * 64 + 255) / 256, 256, 0, stream>>>(ea, nn1_w, nn1_b, u);
  k_deg<<<(NE + 255) / 256, 256, 0, stream>>>(ei, deg);
  k_scan<<<1, 256, 0, stream>>>(deg, offs, invd);
  k_csr<<<(NE + 255) / 256, 256, 0, stream>>>(ei, offs, cursor, csr_src, csr_eid);
  k_wf<<<(KTOT * 64 + 255) / 256, 256, 0, stream>>>(nn2_w, nn2_b, root_w, wf);

  float* hc = h0;
  float* hn = h1;
  for (int it = 0; it < 3; ++it) {
    for (int cs = 0; cs < NN; cs += (int)CH) {
      int cn = (NN - cs < (int)CH) ? (NN - cs) : (int)CH;
      k_scatter<<<cn, 256, 0, stream>>>(hc, u, offs, csr_src, csr_eid, invd, sv, cs);
      dim3 g2((cn + 63) / 64, SPLITK);
      k_gemm2<<<g2, 256, 0, stream>>>(sv, wf, kpart, cs, cn);
    }
    k_epi<<<(NN * 64 + 255) / 256, 256, 0, stream>>>(kpart, conv_b, hn);
    float* tmp = hc; hc = hn; hn = tmp;
  }
  k_sum_p<<<160, 256, 0, stream>>>(hc, part);
  k_bneck<<<1, 384, 0, stream>>>(part, vpa, mz, adduct, bw, bb, actA);
  float* ain = actA;
  float* aout = actB;
  for (int L = 0; L < 6; ++L) {
    k_layer<<<24, 256, 0, stream>>>(ain, l1w, l1b, aout);
    float* tmp = ain; ain = aout; aout = tmp;
  }
  k_out<<<1, 384, 0, stream>>>(ain, l2w, l2b, (float*)d_out);
}